// Round 8
// baseline (1315.574 us; speedup 1.0000x reference)
//
#include <hip/hip_runtime.h>
#include <hip/hip_bf16.h>

#define N_NODES 100000
#define N_EDGES 640000
#define DD 128
#define DE 32
#define SCAN_B 256
#define SCAN_NB ((N_NODES + SCAN_B - 1) / SCAN_B)   // 391

typedef __attribute__((ext_vector_type(8))) short bf8v;
typedef __attribute__((ext_vector_type(4))) float f4v;

__device__ __forceinline__ float gelu_f(float x) {
    return 0.5f * x * (1.0f + erff(x * 0.70710678118654752f));
}
// gelu(x) = x * sigmoid(2y): z = x*(c1 + c2*x^2) in log2 domain, 8 VALU ops.
__device__ __forceinline__ float gelu_t(float x) {
    float x2 = x * x;
    float z = x * fmaf(0.1029437f, x2, 2.3022082f);
    float e = __builtin_amdgcn_exp2f(z);
    float r = __builtin_amdgcn_rcpf(e + 1.0f);
    return fmaf(-x, r, x);
}
__device__ __forceinline__ float bf2f(ushort u) {
    union { uint u; float f; } t; t.u = ((uint)u) << 16; return t.f;
}
__device__ __forceinline__ ushort f2bf(float f) {
    union { float f; uint u; } t; t.f = f;
    uint r = (t.u + 0x7fffu + ((t.u >> 16) & 1u)) >> 16;
    return (ushort)r;
}

// ---- cooperative weight staging: 128x128 bf16 tile -> 32KB LDS, XOR-swizzled ----
// LDS dest linear (wave-uniform base + lane*16); swizzle applied to GLOBAL source.
template<int NW>
__device__ __forceinline__ void stage_w(ushort* lwgt, const ushort* __restrict__ src,
                                        int stride, int w, int lane) {
    constexpr int SEG = 32768 / NW;        // bytes per wave
#pragma unroll
    for (int k = 0; k < SEG / 1024; k++) {
        int o = w * SEG + k * 1024 + lane * 16;      // linear LDS byte offset
        int row = o >> 8;                            // 0..127
        int swz = o ^ ((row & 7) << 4);              // involution
        const ushort* g = src + (size_t)row * stride + ((swz & 255) >> 1);
        __builtin_amdgcn_global_load_lds(
            (const __attribute__((address_space(1))) void*)g,
            (__attribute__((address_space(3))) void*)(lwgt + (w * SEG + k * 1024) / 2),
            16, 0, 0);
    }
}

// ---- 16-row x 128-col GEMM from staged LDS weights ----
__device__ __forceinline__ void gemm_l(const bf8v* a, const ushort* lwgt,
                                       int cq, int quad, f4v* acc) {
    const char* lb = (const char*)lwgt;
    int sw = (cq & 7) << 4;
    __builtin_amdgcn_s_setprio(1);
#pragma unroll
    for (int ct = 0; ct < 8; ct++) {
#pragma unroll
        for (int kc = 0; kc < 4; kc++) {
            int addr = (((ct * 16 + cq) << 8) + (kc << 6) + (quad << 4)) ^ sw;
            acc[ct] = __builtin_amdgcn_mfma_f32_16x16x32_bf16(a[kc],
                *(const bf8v*)(lb + addr), acc[ct], 0, 0, 0);
        }
    }
    __builtin_amdgcn_s_setprio(0);
}

// ---------------- CSR build ----------------
__global__ void k_count(const int* __restrict__ ei, int* __restrict__ cnt) {
    int e = blockIdx.x * blockDim.x + threadIdx.x;
    if (e < N_EDGES) atomicAdd(&cnt[ei[N_EDGES + e]], 1);
}

__global__ void k_scan1(const int* __restrict__ cnt, int* __restrict__ bsum) {
    __shared__ int s[SCAN_B];
    int i = blockIdx.x * SCAN_B + threadIdx.x;
    int v = (i < N_NODES) ? cnt[i] : 0;
    s[threadIdx.x] = v;
    __syncthreads();
    for (int off = SCAN_B / 2; off > 0; off >>= 1) {
        if (threadIdx.x < off) s[threadIdx.x] += s[threadIdx.x + off];
        __syncthreads();
    }
    if (threadIdx.x == 0) bsum[blockIdx.x] = s[0];
}

__global__ void k_scan2(int* __restrict__ bsum) {
    __shared__ int s[512];
    int t = threadIdx.x;
    int v = (t < SCAN_NB) ? bsum[t] : 0;
    s[t] = v;
    __syncthreads();
    for (int off = 1; off < 512; off <<= 1) {
        int u = (t >= off) ? s[t - off] : 0;
        __syncthreads();
        s[t] += u;
        __syncthreads();
    }
    if (t < SCAN_NB) bsum[t] = s[t] - v;   // exclusive
}

__global__ void k_scan3(const int* __restrict__ cnt, const int* __restrict__ bsum,
                        int* __restrict__ cursor, float* __restrict__ flag,
                        float* __restrict__ invdeg) {
    __shared__ int s[SCAN_B];
    int i = blockIdx.x * SCAN_B + threadIdx.x;
    int v = (i < N_NODES) ? cnt[i] : 0;
    s[threadIdx.x] = v;
    __syncthreads();
    for (int off = 1; off < SCAN_B; off <<= 1) {
        int u = (threadIdx.x >= off) ? s[threadIdx.x - off] : 0;
        __syncthreads();
        s[threadIdx.x] += u;
        __syncthreads();
    }
    if (i < N_NODES) {
        int excl = s[threadIdx.x] - v + bsum[blockIdx.x];
        cursor[i] = excl;
        flag[i] = (v > 0) ? 1.0f : 0.0f;
        invdeg[i] = (v > 0) ? 1.0f / (float)v : 0.0f;
    }
}

// scatter + inline edge_attr permute (fp32 -> bf16, CSR slot order)
__global__ void k_scatter(const int* __restrict__ ei, const float* __restrict__ ea,
                          int* __restrict__ cursor, int* __restrict__ esrc,
                          int* __restrict__ edst, ushort* __restrict__ eat) {
    int e = blockIdx.x * blockDim.x + threadIdx.x;
    if (e < N_EDGES) {
        int d = ei[N_EDGES + e];
        int pos = atomicAdd(&cursor[d], 1);
        esrc[pos] = ei[e];
        edst[pos] = d;
        const float* s = ea + (size_t)e * DE;
        ushort* o = eat + (size_t)pos * DE;
#pragma unroll
        for (int k = 0; k < 8; k++) {
            float4 v = *(const float4*)(s + k * 4);
            ushort4 u;
            u.x = f2bf(v.x); u.y = f2bf(v.y); u.z = f2bf(v.z); u.w = f2bf(v.w);
            *(ushort4*)(o + k * 4) = u;
        }
    }
}

// ---------------- composite edge weights: writes bf16-transposed WeT + fp32 bc ----------------
__global__ void k_prep(const float* __restrict__ edge_w, const float* __restrict__ edge_b,
                       const float* __restrict__ msg_w1, const float* __restrict__ msg_b1,
                       ushort* __restrict__ WeT, float* __restrict__ bc) {
    int j = threadIdx.x;
    int c = blockIdx.x;
    int l = blockIdx.y;
    const float* w1 = msg_w1 + (size_t)l * DD * DD;
    if (c < DE) {
        float s = 0.0f;
        for (int k = 0; k < DD; k++) s += edge_w[c*DD + k] * w1[k*DD + j];
        WeT[((size_t)l*DD + j)*DE + c] = f2bf(s);     // [l][j(out)][c(k)]
    } else {
        float s = msg_b1[l*DD + j];
        for (int k = 0; k < DD; k++) s += edge_b[k] * w1[k*DD + j];
        bc[l*DD + j] = s;
    }
}

// ---------------- batched transpose fp32 [R][C] -> bf16 [C][R] ----------------
struct TDesc { const float* src; ushort* dst; int R; int C; };
struct TPack { TDesc d[13]; };

__global__ void k_tball(TPack p) {
    TDesc t = p.d[blockIdx.y];
    int idx = blockIdx.x * 256 + threadIdx.x;
    if (idx < t.R * t.C) {
        int r = idx / t.C, c = idx % t.C;
        t.dst[(size_t)c * t.R + r] = f2bf(t.src[idx]);
    }
}

// ---------------- embed + fused nodeW1(l=0), LDS-staged weights (4-wave) ----------------
__global__ __launch_bounds__(256, 3) void k_embed(
    const float* __restrict__ x, const ushort* __restrict__ WT,
    const float* __restrict__ bias, const ushort* __restrict__ W1T,
    float* __restrict__ node, ushort* __restrict__ slotA, int M)
{
    __shared__ __align__(16) ushort lwgt[16384];   // 32KB staged weight tile
    __shared__ ushort tr[4][16 * 136];
    int tid = threadIdx.x, lane = tid & 63, w = tid >> 6;
    int base = (blockIdx.x * 4 + w) * 16;
    bool act = base < M;
    int cq = lane & 15, quad = lane >> 4;
    ushort* trw = tr[w];
    f4v acc[8];
    bf8v a[4];

    stage_w<4>(lwgt, WT, DD, w, lane);              // phase 0 weights in flight
    if (act) {
        const float* Af = x + (size_t)(base + cq) * DD;
#pragma unroll
        for (int kc = 0; kc < 4; kc++) {
            float4 v0 = *(const float4*)(Af + kc * 32 + quad * 8);
            float4 v1 = *(const float4*)(Af + kc * 32 + quad * 8 + 4);
            bf8v t;
            t[0]=(short)f2bf(v0.x); t[1]=(short)f2bf(v0.y); t[2]=(short)f2bf(v0.z); t[3]=(short)f2bf(v0.w);
            t[4]=(short)f2bf(v1.x); t[5]=(short)f2bf(v1.y); t[6]=(short)f2bf(v1.z); t[7]=(short)f2bf(v1.w);
            a[kc] = t;
        }
    }
    __syncthreads();                                // staging complete
    int r0 = base + quad * 4;
    bf8v a2[4];
    if (act) {
#pragma unroll
        for (int ct = 0; ct < 8; ct++) acc[ct] = 0.0f;
        gemm_l(a, lwgt, cq, quad, acc);
#pragma unroll
        for (int ct = 0; ct < 8; ct++) {
            int col = ct * 16 + cq;
            float b_ = bias[col];
#pragma unroll
            for (int i = 0; i < 4; i++) {
                float v = acc[ct][i] + b_;
                node[(size_t)(r0 + i) * DD + col] = v;
                trw[(quad * 4 + i) * 136 + col] = f2bf(v);
            }
        }
#pragma unroll
        for (int kc = 0; kc < 4; kc++)
            a2[kc] = *(const bf8v*)(trw + cq * 136 + kc * 32 + quad * 8);
    }
    __syncthreads();                                // all waves done reading lwgt
    stage_w<4>(lwgt, W1T, DD, w, lane);
    __syncthreads();
    if (act) {
#pragma unroll
        for (int ct = 0; ct < 8; ct++) acc[ct] = 0.0f;
        gemm_l(a2, lwgt, cq, quad, acc);
#pragma unroll
        for (int ct = 0; ct < 8; ct++) {
            int col = ct * 16 + cq;
#pragma unroll
            for (int i = 0; i < 4; i++)
                slotA[(size_t)(r0 + i) * DD + col] = f2bf(acc[ct][i]);
        }
    }
}

// ---------------- fused edge message + segmented aggregation ----------------
__global__ __launch_bounds__(256) void k_msg(
    const ushort* __restrict__ eat,
    const ushort* __restrict__ WeT, const float* __restrict__ bcv,
    const int* __restrict__ esrc, const int* __restrict__ edst,
    const ushort* __restrict__ slotA, float* __restrict__ aggf)
{
    __shared__ ushort tr[4][16 * 136];
    __shared__ int2 sd[4][16];
    int tid = threadIdx.x, lane = tid & 63, w = tid >> 6;
    int jt = (blockIdx.x * 4 + w) * 16;
    int cq = lane & 15, quad = lane >> 4;
    ushort* trw = tr[w];

    if (lane < 16) {
        int2 v; v.x = esrc[jt + lane]; v.y = edst[jt + lane];
        sd[w][lane] = v;
    }
    // ---- A: per-edge embedding via MFMA (K=32), sequential bf16 edge reads ----
    {
        bf8v a = *(const bf8v*)(eat + (size_t)(jt + cq) * DE + quad * 8);
        __builtin_amdgcn_s_setprio(1);
#pragma unroll
        for (int ct = 0; ct < 8; ct++) {
            bf8v b = *(const bf8v*)(WeT + (size_t)(ct * 16 + cq) * DE + quad * 8);
            f4v z; z = 0.0f;
            f4v r = __builtin_amdgcn_mfma_f32_16x16x32_bf16(a, b, z, 0, 0, 0);
            int col = ct * 16 + cq;
            float b_ = bcv[col];
#pragma unroll
            for (int i = 0; i < 4; i++)
                trw[(quad * 4 + i) * 136 + col] = f2bf(r[i] + b_);
        }
        __builtin_amdgcn_s_setprio(0);
    }
    // ---- B: prefetch all 16 src-row gathers, then gelu + segmented sums ----
    uint nwv[16];
#pragma unroll
    for (int r = 0; r < 16; r++)
        nwv[r] = *(const uint*)(slotA + (size_t)sd[w][r].x * DD + 2 * lane);
    float a0 = 0.0f, a1 = 0.0f;
    int rstart = 0;
#pragma unroll
    for (int r = 0; r < 16; r++) {
        int dcur = sd[w][r].y;
        uint em = *(const uint*)(trw + r * 136 + 2 * lane);
        uint nw = nwv[r];
        a0 += gelu_t(bf2f((ushort)(em & 0xffffu)) + bf2f((ushort)(nw & 0xffffu)));
        a1 += gelu_t(bf2f((ushort)(em >> 16)) + bf2f((ushort)(nw >> 16)));
        bool flush = (r == 15) || (sd[w][r + 1].y != dcur);
        if (flush) {
            float* p = aggf + (size_t)dcur * DD + 2 * lane;
            if (rstart > 0 && r < 15) {
                float2 st; st.x = a0; st.y = a1;
                *(float2*)p = st;                  // sole writer: plain store
            } else {
                atomicAdd(p, a0);
                atomicAdd(p + 1, a1);
            }
            a0 = 0.0f; a1 = 0.0f; rstart = r + 1;
        }
    }
}

// ---------------- mega node MLP: 32 rows/wave, SINGLE shared tr buffer ----------------
// Two 16-row tiles sequentially reuse one 16x136 transpose buffer (intra-wave
// write->read is immediate); fragments held in registers across staging barriers.
// LDS stays at 50176 (3 blocks/CU) while staging is amortized over 128 rows/block.
template<int FUSE>
__global__ __launch_bounds__(256, 3) void k_mlp(
    float* __restrict__ aggf, const float* __restrict__ invdeg,
    const ushort* __restrict__ w2T, const float* __restrict__ b2,
    const float* __restrict__ flag,
    const ushort* __restrict__ u1T, const float* __restrict__ bu1,
    const ushort* __restrict__ u2T, const float* __restrict__ bu2,
    float* __restrict__ node,
    const float* __restrict__ lg, const float* __restrict__ lb,
    const ushort* __restrict__ w1nT, ushort* __restrict__ slotA, int M)
{
    __shared__ __align__(16) ushort lwgt[16384];   // 32KB staged weight tile
    __shared__ ushort tr[4][16 * 136];
    int tid = threadIdx.x, lane = tid & 63, w = tid >> 6;
    int base = (blockIdx.x * 4 + w) * 32;
    bool act = base < M;
    int cq = lane & 15, quad = lane >> 4;
    ushort* trw = tr[w];
    f4v acc[8], accU0[8], accU1[8];
    bf8v a2_0[4], a2_1[4];

    // ---- phase 0: B1 = (aggf*invdeg) @ msg_w2, both tiles ----
    stage_w<4>(lwgt, w2T, DD, w, lane);
    bf8v a0[4], a1[4];
    if (act) {
        float iv0 = invdeg[base + cq];
        float iv1 = invdeg[base + 16 + cq];
        float* Af0 = aggf + (size_t)(base + cq) * DD;
        float* Af1 = aggf + (size_t)(base + 16 + cq) * DD;
#pragma unroll
        for (int kc = 0; kc < 4; kc++) {
            float4 v0 = *(const float4*)(Af0 + kc * 32 + quad * 8);
            float4 v1 = *(const float4*)(Af0 + kc * 32 + quad * 8 + 4);
            bf8v t;
            t[0]=(short)f2bf(v0.x*iv0); t[1]=(short)f2bf(v0.y*iv0);
            t[2]=(short)f2bf(v0.z*iv0); t[3]=(short)f2bf(v0.w*iv0);
            t[4]=(short)f2bf(v1.x*iv0); t[5]=(short)f2bf(v1.y*iv0);
            t[6]=(short)f2bf(v1.z*iv0); t[7]=(short)f2bf(v1.w*iv0);
            a0[kc] = t;
            float4 w0 = *(const float4*)(Af1 + kc * 32 + quad * 8);
            float4 w1 = *(const float4*)(Af1 + kc * 32 + quad * 8 + 4);
            bf8v s;
            s[0]=(short)f2bf(w0.x*iv1); s[1]=(short)f2bf(w0.y*iv1);
            s[2]=(short)f2bf(w0.z*iv1); s[3]=(short)f2bf(w0.w*iv1);
            s[4]=(short)f2bf(w1.x*iv1); s[5]=(short)f2bf(w1.y*iv1);
            s[6]=(short)f2bf(w1.z*iv1); s[7]=(short)f2bf(w1.w*iv1);
            a1[kc] = s;
        }
        if (FUSE) {
            float4 z4; z4.x = 0.0f; z4.y = 0.0f; z4.z = 0.0f; z4.w = 0.0f;
#pragma unroll
            for (int kc = 0; kc < 4; kc++) {
                *(float4*)(Af0 + kc * 32 + quad * 8) = z4;
                *(float4*)(Af0 + kc * 32 + quad * 8 + 4) = z4;
                *(float4*)(Af1 + kc * 32 + quad * 8) = z4;
                *(float4*)(Af1 + kc * 32 + quad * 8 + 4) = z4;
            }
        }
    }
    __syncthreads();
    if (act) {
        float fl[4];
        // tile 0 (tr reused below — intra-wave write->read)
#pragma unroll
        for (int ct = 0; ct < 8; ct++) acc[ct] = 0.0f;
        gemm_l(a0, lwgt, cq, quad, acc);
#pragma unroll
        for (int i = 0; i < 4; i++) fl[i] = flag[base + quad * 4 + i];
#pragma unroll
        for (int ct = 0; ct < 8; ct++) {
            int col = ct * 16 + cq;
            float b_ = b2[col];
#pragma unroll
            for (int i = 0; i < 4; i++)
                trw[(quad * 4 + i) * 136 + col] = f2bf(acc[ct][i] + fl[i] * b_);
        }
#pragma unroll
        for (int kc = 0; kc < 4; kc++)
            a2_0[kc] = *(const bf8v*)(trw + cq * 136 + kc * 32 + quad * 8);
        // tile 1 (overwrite tr)
#pragma unroll
        for (int ct = 0; ct < 8; ct++) acc[ct] = 0.0f;
        gemm_l(a1, lwgt, cq, quad, acc);
#pragma unroll
        for (int i = 0; i < 4; i++) fl[i] = flag[base + 16 + quad * 4 + i];
#pragma unroll
        for (int ct = 0; ct < 8; ct++) {
            int col = ct * 16 + cq;
            float b_ = b2[col];
#pragma unroll
            for (int i = 0; i < 4; i++)
                trw[(quad * 4 + i) * 136 + col] = f2bf(acc[ct][i] + fl[i] * b_);
        }
#pragma unroll
        for (int kc = 0; kc < 4; kc++)
            a2_1[kc] = *(const bf8v*)(trw + cq * 136 + kc * 32 + quad * 8);
    }

    // ---- u = gelu(a2@u1 + bu1) @ u2, two 128-col halves, both tiles ----
#pragma unroll
    for (int ct = 0; ct < 8; ct++) { accU0[ct] = 0.0f; accU1[ct] = 0.0f; }
#pragma unroll
    for (int h = 0; h < 2; h++) {
        __syncthreads();                            // readers done with lwgt
        stage_w<4>(lwgt, u1T + (size_t)h * 128 * DD, DD, w, lane);
        __syncthreads();                            // u1 half staged
        bf8v tf0[4], tf1[4];
        if (act) {
            // tile 0: gemm -> gelu -> tr -> fragments to regs
#pragma unroll
            for (int ct = 0; ct < 8; ct++) acc[ct] = 0.0f;
            gemm_l(a2_0, lwgt, cq, quad, acc);
#pragma unroll
            for (int ct = 0; ct < 8; ct++) {
                int col = ct * 16 + cq;
                float b_ = bu1[h * 128 + col];
#pragma unroll
                for (int i = 0; i < 4; i++)
                    trw[(quad * 4 + i) * 136 + col] = f2bf(gelu_f(acc[ct][i] + b_));
            }
#pragma unroll
            for (int kc = 0; kc < 4; kc++)
                tf0[kc] = *(const bf8v*)(trw + cq * 136 + kc * 32 + quad * 8);
            // tile 1 (overwrite tr)
#pragma unroll
            for (int ct = 0; ct < 8; ct++) acc[ct] = 0.0f;
            gemm_l(a2_1, lwgt, cq, quad, acc);
#pragma unroll
            for (int ct = 0; ct < 8; ct++) {
                int col = ct * 16 + cq;
                float b_ = bu1[h * 128 + col];
#pragma unroll
                for (int i = 0; i < 4; i++)
                    trw[(quad * 4 + i) * 136 + col] = f2bf(gelu_f(acc[ct][i] + b_));
            }
#pragma unroll
            for (int kc = 0; kc < 4; kc++)
                tf1[kc] = *(const bf8v*)(trw + cq * 136 + kc * 32 + quad * 8);
        }
        __syncthreads();
        stage_w<4>(lwgt, u2T + (size_t)h * 128, 256, w, lane);   // u2 half, stride 256
        __syncthreads();
        if (act) {
            gemm_l(tf0, lwgt, cq, quad, accU0);
            gemm_l(tf1, lwgt, cq, quad, accU1);
        }
    }

    // ---- resid + LN, both tiles; FUSE fragments captured via shared tr ----
    bf8v nf0[4], nf1[4];
    if (act) {
        // tile 0
        {
            int r0 = base + quad * 4;
            float xv[8][4], lgc[8], lbc[8];
#pragma unroll
            for (int ct = 0; ct < 8; ct++) {
                int col = ct * 16 + cq;
                float b_ = bu2[col];
                lgc[ct] = lg[col]; lbc[ct] = lb[col];
#pragma unroll
                for (int i = 0; i < 4; i++)
                    xv[ct][i] = accU0[ct][i] + b_ + node[(size_t)(r0 + i) * DD + col];
            }
#pragma unroll
            for (int i = 0; i < 4; i++) {
                float s = 0.0f;
#pragma unroll
                for (int ct = 0; ct < 8; ct++) s += xv[ct][i];
                s += __shfl_xor(s, 1); s += __shfl_xor(s, 2);
                s += __shfl_xor(s, 4); s += __shfl_xor(s, 8);
                float m = s * (1.0f / 128.0f);
                float vv = 0.0f;
#pragma unroll
                for (int ct = 0; ct < 8; ct++) { float d = xv[ct][i] - m; vv += d * d; }
                vv += __shfl_xor(vv, 1); vv += __shfl_xor(vv, 2);
                vv += __shfl_xor(vv, 4); vv += __shfl_xor(vv, 8);
                float inv = rsqrtf(vv * (1.0f / 128.0f) + 1e-5f);
#pragma unroll
                for (int ct = 0; ct < 8; ct++) {
                    int col = ct * 16 + cq;
                    float y = (xv[ct][i] - m) * inv * lgc[ct] + lbc[ct];
                    node[(size_t)(r0 + i) * DD + col] = y;
                    if (FUSE) trw[(quad * 4 + i) * 136 + col] = f2bf(y);
                }
            }
            if (FUSE) {
#pragma unroll
                for (int kc = 0; kc < 4; kc++)
                    nf0[kc] = *(const bf8v*)(trw + cq * 136 + kc * 32 + quad * 8);
            }
        }
        // tile 1
        {
            int r0 = base + 16 + quad * 4;
            float xv[8][4], lgc[8], lbc[8];
#pragma unroll
            for (int ct = 0; ct < 8; ct++) {
                int col = ct * 16 + cq;
                float b_ = bu2[col];
                lgc[ct] = lg[col]; lbc[ct] = lb[col];
#pragma unroll
                for (int i = 0; i < 4; i++)
                    xv[ct][i] = accU1[ct][i] + b_ + node[(size_t)(r0 + i) * DD + col];
            }
#pragma unroll
            for (int i = 0; i < 4; i++) {
                float s = 0.0f;
#pragma unroll
                for (int ct = 0; ct < 8; ct++) s += xv[ct][i];
                s += __shfl_xor(s, 1); s += __shfl_xor(s, 2);
                s += __shfl_xor(s, 4); s += __shfl_xor(s, 8);
                float m = s * (1.0f / 128.0f);
                float vv = 0.0f;
#pragma unroll
                for (int ct = 0; ct < 8; ct++) { float d = xv[ct][i] - m; vv += d * d; }
                vv += __shfl_xor(vv, 1); vv += __shfl_xor(vv, 2);
                vv += __shfl_xor(vv, 4); vv += __shfl_xor(vv, 8);
                float inv = rsqrtf(vv * (1.0f / 128.0f) + 1e-5f);
#pragma unroll
                for (int ct = 0; ct < 8; ct++) {
                    int col = ct * 16 + cq;
                    float y = (xv[ct][i] - m) * inv * lgc[ct] + lbc[ct];
                    node[(size_t)(r0 + i) * DD + col] = y;
                    if (FUSE) trw[(quad * 4 + i) * 136 + col] = f2bf(y);
                }
            }
            if (FUSE) {
#pragma unroll
                for (int kc = 0; kc < 4; kc++)
                    nf1[kc] = *(const bf8v*)(trw + cq * 136 + kc * 32 + quad * 8);
            }
        }
    }

    // ---- fused next-layer nodeW1, both tiles ----
    if (FUSE) {
        __syncthreads();
        stage_w<4>(lwgt, w1nT, DD, w, lane);
        __syncthreads();
        if (act) {
#pragma unroll
            for (int ct = 0; ct < 8; ct++) acc[ct] = 0.0f;
            gemm_l(nf0, lwgt, cq, quad, acc);
            int r0 = base + quad * 4;
#pragma unroll
            for (int ct = 0; ct < 8; ct++) {
                int col = ct * 16 + cq;
#pragma unroll
                for (int i = 0; i < 4; i++)
                    slotA[(size_t)(r0 + i) * DD + col] = f2bf(acc[ct][i]);
            }
#pragma unroll
            for (int ct = 0; ct < 8; ct++) acc[ct] = 0.0f;
            gemm_l(nf1, lwgt, cq, quad, acc);
            int r1 = base + 16 + quad * 4;
#pragma unroll
            for (int ct = 0; ct < 8; ct++) {
                int col = ct * 16 + cq;
#pragma unroll
                for (int i = 0; i < 4; i++)
                    slotA[(size_t)(r1 + i) * DD + col] = f2bf(acc[ct][i]);
            }
        }
    }
}

// ---------------- pooling: 128 chunks/segment for latency hiding ----------------
__global__ void k_pool_partial(const float* __restrict__ node, float* __restrict__ partial) {
    int seg = blockIdx.x, chunk = blockIdx.y, j = threadIdx.x;
    int segbase = seg * 14286;
    int segcnt = (seg == 6) ? 14284 : 14286;
    const int per = 112;                       // ceil(14286/128)
    int lo = chunk * per, hi = min(lo + per, segcnt);
    float s = 0.0f;
    for (int r = lo; r < hi; r++) s += node[(size_t)(segbase + r) * DD + j];
    partial[(size_t)(seg * 128 + chunk) * DD + j] = s;
}

__global__ void k_pool_final(const float* __restrict__ partial, const float* __restrict__ g,
                             const float* __restrict__ b, float* __restrict__ out) {
    __shared__ float red[128];
    int j = threadIdx.x;
    float tok[8];
    float tot = 0.0f;
#pragma unroll
    for (int s = 0; s < 7; s++) {
        float v = 0.0f;
        for (int c = 0; c < 128; c++) v += partial[(size_t)(s * 128 + c) * DD + j];
        tok[1 + s] = v / ((s == 6) ? 14284.0f : 14286.0f);
        tot += v;
    }
    tok[0] = tot / 100000.0f;
    for (int t = 0; t < 8; t++) {
        float x = tok[t];
        red[j] = x; __syncthreads();
        for (int off = 64; off > 0; off >>= 1) {
            if (j < off) red[j] += red[j + off];
            __syncthreads();
        }
        float m = red[0] / 128.0f;
        __syncthreads();
        float d = x - m;
        red[j] = d * d; __syncthreads();
        for (int off = 64; off > 0; off >>= 1) {
            if (j < off) red[j] += red[j + off];
            __syncthreads();
        }
        float var = red[0] / 128.0f;
        __syncthreads();
        out[t * DD + j] = d * rsqrtf(var + 1e-5f) * g[j] + b[j];
    }
}

extern "C" void kernel_launch(void* const* d_in, const int* in_sizes, int n_in,
                              void* d_out, int out_size, void* d_ws, size_t ws_size,
                              hipStream_t stream) {
    const float* x         = (const float*)d_in[0];
    const int*   ei        = (const int*)d_in[1];
    const float* edge_attr = (const float*)d_in[2];
    const float* node_w    = (const float*)d_in[3];
    const float* node_b    = (const float*)d_in[4];
    const float* edge_w    = (const float*)d_in[5];
    const float* edge_b    = (const float*)d_in[6];
    const float* msg_w1    = (const float*)d_in[7];
    const float* msg_b1    = (const float*)d_in[8];
    const float* msg_w2    = (const float*)d_in[9];
    const float* msg_b2    = (const float*)d_in[10];
    const float* upd_w1    = (const float*)d_in[11];
    const float* upd_b1    = (const float*)d_in[12];
    const float* upd_w2    = (const float*)d_in[13];
    const float* upd_b2    = (const float*)d_in[14];
    const float* ln_g      = (const float*)d_in[15];
    const float* ln_b      = (const float*)d_in[16];
    const float* out_g     = (const float*)d_in[17];
    const float* out_b     = (const float*)d_in[18];
    float* out = (float*)d_out;

    // ---- workspace layout ----
    char* pw = (char*)d_ws;
    auto alloc = [&](size_t bytes) -> void* {
        void* r = (void*)pw;
        pw += (bytes + 255) & ~(size_t)255;
        return r;
    };
    float*  node_f  = (float*) alloc((size_t)N_NODES * DD * 4);
    ushort* slotA   = (ushort*)alloc((size_t)N_NODES * DD * 2);
    float*  aggf    = (float*) alloc((size_t)N_NODES * DD * 4);
    ushort* eat     = (ushort*)alloc((size_t)N_EDGES * DE * 2);
    float*  bc      = (float*) alloc((size_t)3 * DD * 4);
    ushort* WeT     = (ushort*)alloc((size_t)3 * DD * DE * 2);
    float*  partial = (float*) alloc((size_t)7 * 128 * DD * 4);
    float*  degflag = (float*) alloc((size_t)N_NODES * 4);
    float*  invdeg  = (float*) alloc((size_t)N_NODES * 4);
    ushort* node_wT = (ushort*)alloc((size_t)DD * DD * 2);
    ushort* msg_w1T = (ushort*)alloc((size_t)3 * DD * DD * 2);
    ushort* msg_w2T = (ushort*)alloc((size_t)3 * DD * DD * 2);
    ushort* upd_w1T = (ushort*)alloc((size_t)3 * 256 * DD * 2);
    ushort* upd_w2T = (ushort*)alloc((size_t)3 * DD * 256 * 2);
    int* cnt        = (int*)   alloc((size_t)N_NODES * 4);
    int* cursor     = (int*)   alloc((size_t)N_NODES * 4);
    int* bsum       = (int*)   alloc((size_t)512 * 4);
    int* esrc       = (int*)   alloc((size_t)N_EDGES * 4);
    int* edst       = (int*)   alloc((size_t)N_EDGES * 4);

    hipMemsetAsync(cnt, 0, N_NODES * sizeof(int), stream);
    hipMemsetAsync(aggf, 0, (size_t)N_NODES * DD * 4, stream);   // layer-0 agg init
    k_count  <<<(N_EDGES + 255) / 256, 256, 0, stream>>>(ei, cnt);
    k_scan1  <<<SCAN_NB, SCAN_B, 0, stream>>>(cnt, bsum);
    k_scan2  <<<1, 512, 0, stream>>>(bsum);
    k_scan3  <<<SCAN_NB, SCAN_B, 0, stream>>>(cnt, bsum, cursor, degflag, invdeg);
    k_scatter<<<(N_EDGES + 255) / 256, 256, 0, stream>>>(ei, edge_attr, cursor, esrc, edst, eat);
    k_prep   <<<dim3(DE + 1, 3), DD, 0, stream>>>(edge_w, edge_b, msg_w1, msg_b1, WeT, bc);

    // batched weight transposes -> bf16 [out][in]
    TPack tp;
    tp.d[0] = { node_w, node_wT, DD, DD };
    for (int l = 0; l < 3; l++) {
        tp.d[1 + l*4 + 0] = { msg_w1 + (size_t)l*DD*DD,  msg_w1T + (size_t)l*DD*DD,  DD, DD };
        tp.d[1 + l*4 + 1] = { msg_w2 + (size_t)l*DD*DD,  msg_w2T + (size_t)l*DD*DD,  DD, DD };
        tp.d[1 + l*4 + 2] = { upd_w1 + (size_t)l*DD*256, upd_w1T + (size_t)l*256*DD, DD, 256 };
        tp.d[1 + l*4 + 3] = { upd_w2 + (size_t)l*256*DD, upd_w2T + (size_t)l*DD*256, 256, DD };
    }
    k_tball<<<dim3(128, 13), 256, 0, stream>>>(tp);

    const int GB = (N_NODES / 16 + 3) / 4;     // 1563 (k_embed, 16 rows/wave)
    const int GB32 = (N_NODES / 32 + 3) / 4;   // 782  (k_mlp, 32 rows/wave)
    const int MSG_GB = N_EDGES / 64;           // 10000
    k_embed<<<GB, 256, 0, stream>>>(x, node_wT, node_b, msg_w1T, node_f, slotA, N_NODES);

    for (int l = 0; l < 3; l++) {
        k_msg<<<MSG_GB, 256, 0, stream>>>(eat, WeT + (size_t)l*DD*DE,
            bc + (size_t)l*DD, esrc, edst, slotA, aggf);
        if (l < 2) {
            k_mlp<1><<<GB32, 256, 0, stream>>>(aggf, invdeg,
                msg_w2T + (size_t)l*DD*DD, msg_b2 + (size_t)l*DD, degflag,
                upd_w1T + (size_t)l*256*DD, upd_b1 + (size_t)l*256,
                upd_w2T + (size_t)l*DD*256, upd_b2 + (size_t)l*DD,
                node_f, ln_g + (size_t)l*DD, ln_b + (size_t)l*DD,
                msg_w1T + (size_t)(l+1)*DD*DD, slotA, N_NODES);
        } else {
            k_mlp<0><<<GB32, 256, 0, stream>>>(aggf, invdeg,
                msg_w2T + (size_t)l*DD*DD, msg_b2 + (size_t)l*DD, degflag,
                upd_w1T + (size_t)l*256*DD, upd_b1 + (size_t)l*256,
                upd_w2T + (size_t)l*DD*256, upd_b2 + (size_t)l*DD,
                node_f, ln_g + (size_t)l*DD, ln_b + (size_t)l*DD,
                msg_w1T, slotA, N_NODES);
        }
    }

    k_pool_partial<<<dim3(7, 128), DD, 0, stream>>>(node_f, partial);
    k_pool_final  <<<1, DD, 0, stream>>>(partial, out_g, out_b, out);
}

// Round 9
// 818.460 us; speedup vs baseline: 1.6074x; 1.6074x over previous
//
#include <hip/hip_runtime.h>
#include <hip/hip_bf16.h>

#define N_NODES 100000
#define N_EDGES 640000
#define DD 128
#define DE 32
#define SCAN_B 256
#define SCAN_NB ((N_NODES + SCAN_B - 1) / SCAN_B)   // 391

typedef __attribute__((ext_vector_type(8))) short bf8v;
typedef __attribute__((ext_vector_type(4))) float f4v;

__device__ __forceinline__ float gelu_f(float x) {
    return 0.5f * x * (1.0f + erff(x * 0.70710678118654752f));
}
// gelu(x) = x * sigmoid(2y): z = x*(c1 + c2*x^2) in log2 domain, 8 VALU ops.
__device__ __forceinline__ float gelu_t(float x) {
    float x2 = x * x;
    float z = x * fmaf(0.1029437f, x2, 2.3022082f);
    float e = __builtin_amdgcn_exp2f(z);
    float r = __builtin_amdgcn_rcpf(e + 1.0f);
    return fmaf(-x, r, x);
}
__device__ __forceinline__ float bf2f(ushort u) {
    union { uint u; float f; } t; t.u = ((uint)u) << 16; return t.f;
}
__device__ __forceinline__ ushort f2bf(float f) {
    union { float f; uint u; } t; t.f = f;
    uint r = (t.u + 0x7fffu + ((t.u >> 16) & 1u)) >> 16;
    return (ushort)r;
}

// ---- cooperative weight staging: 128x128 bf16 tile -> 32KB LDS, XOR-swizzled ----
// LDS dest linear (wave-uniform base + lane*16); swizzle applied to GLOBAL source.
template<int NW>
__device__ __forceinline__ void stage_w(ushort* lwgt, const ushort* __restrict__ src,
                                        int stride, int w, int lane) {
    constexpr int SEG = 32768 / NW;        // bytes per wave
#pragma unroll
    for (int k = 0; k < SEG / 1024; k++) {
        int o = w * SEG + k * 1024 + lane * 16;      // linear LDS byte offset
        int row = o >> 8;                            // 0..127
        int swz = o ^ ((row & 7) << 4);              // involution
        const ushort* g = src + (size_t)row * stride + ((swz & 255) >> 1);
        __builtin_amdgcn_global_load_lds(
            (const __attribute__((address_space(1))) void*)g,
            (__attribute__((address_space(3))) void*)(lwgt + (w * SEG + k * 1024) / 2),
            16, 0, 0);
    }
}

// ---- 16-row x 128-col GEMM from staged LDS weights ----
__device__ __forceinline__ void gemm_l(const bf8v* a, const ushort* lwgt,
                                       int cq, int quad, f4v* acc) {
    const char* lb = (const char*)lwgt;
    int sw = (cq & 7) << 4;
    __builtin_amdgcn_s_setprio(1);
#pragma unroll
    for (int ct = 0; ct < 8; ct++) {
#pragma unroll
        for (int kc = 0; kc < 4; kc++) {
            int addr = (((ct * 16 + cq) << 8) + (kc << 6) + (quad << 4)) ^ sw;
            acc[ct] = __builtin_amdgcn_mfma_f32_16x16x32_bf16(a[kc],
                *(const bf8v*)(lb + addr), acc[ct], 0, 0, 0);
        }
    }
    __builtin_amdgcn_s_setprio(0);
}

// ---------------- CSR build ----------------
__global__ void k_count(const int* __restrict__ ei, int* __restrict__ cnt) {
    int e = blockIdx.x * blockDim.x + threadIdx.x;
    if (e < N_EDGES) atomicAdd(&cnt[ei[N_EDGES + e]], 1);
}

__global__ void k_scan1(const int* __restrict__ cnt, int* __restrict__ bsum) {
    __shared__ int s[SCAN_B];
    int i = blockIdx.x * SCAN_B + threadIdx.x;
    int v = (i < N_NODES) ? cnt[i] : 0;
    s[threadIdx.x] = v;
    __syncthreads();
    for (int off = SCAN_B / 2; off > 0; off >>= 1) {
        if (threadIdx.x < off) s[threadIdx.x] += s[threadIdx.x + off];
        __syncthreads();
    }
    if (threadIdx.x == 0) bsum[blockIdx.x] = s[0];
}

__global__ void k_scan2(int* __restrict__ bsum) {
    __shared__ int s[512];
    int t = threadIdx.x;
    int v = (t < SCAN_NB) ? bsum[t] : 0;
    s[t] = v;
    __syncthreads();
    for (int off = 1; off < 512; off <<= 1) {
        int u = (t >= off) ? s[t - off] : 0;
        __syncthreads();
        s[t] += u;
        __syncthreads();
    }
    if (t < SCAN_NB) bsum[t] = s[t] - v;   // exclusive
}

__global__ void k_scan3(const int* __restrict__ cnt, const int* __restrict__ bsum,
                        int* __restrict__ cursor, float* __restrict__ flag,
                        float* __restrict__ invdeg) {
    __shared__ int s[SCAN_B];
    int i = blockIdx.x * SCAN_B + threadIdx.x;
    int v = (i < N_NODES) ? cnt[i] : 0;
    s[threadIdx.x] = v;
    __syncthreads();
    for (int off = 1; off < SCAN_B; off <<= 1) {
        int u = (threadIdx.x >= off) ? s[threadIdx.x - off] : 0;
        __syncthreads();
        s[threadIdx.x] += u;
        __syncthreads();
    }
    if (i < N_NODES) {
        int excl = s[threadIdx.x] - v + bsum[blockIdx.x];
        cursor[i] = excl;
        flag[i] = (v > 0) ? 1.0f : 0.0f;
        invdeg[i] = (v > 0) ? 1.0f / (float)v : 0.0f;
    }
}

// scatter + inline edge_attr permute (fp32 -> bf16, CSR slot order)
__global__ void k_scatter(const int* __restrict__ ei, const float* __restrict__ ea,
                          int* __restrict__ cursor, int* __restrict__ esrc,
                          int* __restrict__ edst, ushort* __restrict__ eat) {
    int e = blockIdx.x * blockDim.x + threadIdx.x;
    if (e < N_EDGES) {
        int d = ei[N_EDGES + e];
        int pos = atomicAdd(&cursor[d], 1);
        esrc[pos] = ei[e];
        edst[pos] = d;
        const float* s = ea + (size_t)e * DE;
        ushort* o = eat + (size_t)pos * DE;
#pragma unroll
        for (int k = 0; k < 8; k++) {
            float4 v = *(const float4*)(s + k * 4);
            ushort4 u;
            u.x = f2bf(v.x); u.y = f2bf(v.y); u.z = f2bf(v.z); u.w = f2bf(v.w);
            *(ushort4*)(o + k * 4) = u;
        }
    }
}

// ---------------- composite edge weights: writes bf16-transposed WeT + fp32 bc ----------------
__global__ void k_prep(const float* __restrict__ edge_w, const float* __restrict__ edge_b,
                       const float* __restrict__ msg_w1, const float* __restrict__ msg_b1,
                       ushort* __restrict__ WeT, float* __restrict__ bc) {
    int j = threadIdx.x;
    int c = blockIdx.x;
    int l = blockIdx.y;
    const float* w1 = msg_w1 + (size_t)l * DD * DD;
    if (c < DE) {
        float s = 0.0f;
        for (int k = 0; k < DD; k++) s += edge_w[c*DD + k] * w1[k*DD + j];
        WeT[((size_t)l*DD + j)*DE + c] = f2bf(s);     // [l][j(out)][c(k)]
    } else {
        float s = msg_b1[l*DD + j];
        for (int k = 0; k < DD; k++) s += edge_b[k] * w1[k*DD + j];
        bc[l*DD + j] = s;
    }
}

// ---------------- batched transpose fp32 [R][C] -> bf16 [C][R] ----------------
struct TDesc { const float* src; ushort* dst; int R; int C; };
struct TPack { TDesc d[13]; };

__global__ void k_tball(TPack p) {
    TDesc t = p.d[blockIdx.y];
    int idx = blockIdx.x * 256 + threadIdx.x;
    if (idx < t.R * t.C) {
        int r = idx / t.C, c = idx % t.C;
        t.dst[(size_t)c * t.R + r] = f2bf(t.src[idx]);
    }
}

// ---------------- embed + fused nodeW1(l=0), LDS-staged weights (4-wave) ----------------
__global__ __launch_bounds__(256, 3) void k_embed(
    const float* __restrict__ x, const ushort* __restrict__ WT,
    const float* __restrict__ bias, const ushort* __restrict__ W1T,
    float* __restrict__ node, ushort* __restrict__ slotA, int M)
{
    __shared__ __align__(16) ushort lwgt[16384];   // 32KB staged weight tile
    __shared__ ushort tr[4][16 * 136];
    int tid = threadIdx.x, lane = tid & 63, w = tid >> 6;
    int base = (blockIdx.x * 4 + w) * 16;
    bool act = base < M;
    int cq = lane & 15, quad = lane >> 4;
    ushort* trw = tr[w];
    f4v acc[8];
    bf8v a[4];

    stage_w<4>(lwgt, WT, DD, w, lane);              // phase 0 weights in flight
    if (act) {
        const float* Af = x + (size_t)(base + cq) * DD;
#pragma unroll
        for (int kc = 0; kc < 4; kc++) {
            float4 v0 = *(const float4*)(Af + kc * 32 + quad * 8);
            float4 v1 = *(const float4*)(Af + kc * 32 + quad * 8 + 4);
            bf8v t;
            t[0]=(short)f2bf(v0.x); t[1]=(short)f2bf(v0.y); t[2]=(short)f2bf(v0.z); t[3]=(short)f2bf(v0.w);
            t[4]=(short)f2bf(v1.x); t[5]=(short)f2bf(v1.y); t[6]=(short)f2bf(v1.z); t[7]=(short)f2bf(v1.w);
            a[kc] = t;
        }
    }
    __syncthreads();                                // staging complete
    int r0 = base + quad * 4;
    bf8v a2[4];
    if (act) {
#pragma unroll
        for (int ct = 0; ct < 8; ct++) acc[ct] = 0.0f;
        gemm_l(a, lwgt, cq, quad, acc);
#pragma unroll
        for (int ct = 0; ct < 8; ct++) {
            int col = ct * 16 + cq;
            float b_ = bias[col];
#pragma unroll
            for (int i = 0; i < 4; i++) {
                float v = acc[ct][i] + b_;
                node[(size_t)(r0 + i) * DD + col] = v;
                trw[(quad * 4 + i) * 136 + col] = f2bf(v);
            }
        }
#pragma unroll
        for (int kc = 0; kc < 4; kc++)
            a2[kc] = *(const bf8v*)(trw + cq * 136 + kc * 32 + quad * 8);
    }
    __syncthreads();                                // all waves done reading lwgt
    stage_w<4>(lwgt, W1T, DD, w, lane);
    __syncthreads();
    if (act) {
#pragma unroll
        for (int ct = 0; ct < 8; ct++) acc[ct] = 0.0f;
        gemm_l(a2, lwgt, cq, quad, acc);
#pragma unroll
        for (int ct = 0; ct < 8; ct++) {
            int col = ct * 16 + cq;
#pragma unroll
            for (int i = 0; i < 4; i++)
                slotA[(size_t)(r0 + i) * DD + col] = f2bf(acc[ct][i]);
        }
    }
}

// ---------------- fused edge message + segmented aggregation ----------------
// Per 16-edge CSR tile: emb1 = eat @ WeT + bc (MFMA) -> LDS transpose -> 2 cols/lane.
// slotA row-gathers for all 16 edges issued up-front; interior dst-runs -> plain store.
__global__ __launch_bounds__(256) void k_msg(
    const ushort* __restrict__ eat,
    const ushort* __restrict__ WeT, const float* __restrict__ bcv,
    const int* __restrict__ esrc, const int* __restrict__ edst,
    const ushort* __restrict__ slotA, float* __restrict__ aggf)
{
    __shared__ ushort tr[4][16 * 136];
    __shared__ int2 sd[4][16];
    int tid = threadIdx.x, lane = tid & 63, w = tid >> 6;
    int jt = (blockIdx.x * 4 + w) * 16;
    int cq = lane & 15, quad = lane >> 4;
    ushort* trw = tr[w];

    if (lane < 16) {
        int2 v; v.x = esrc[jt + lane]; v.y = edst[jt + lane];
        sd[w][lane] = v;
    }
    // ---- A: per-edge embedding via MFMA (K=32), sequential bf16 edge reads ----
    {
        bf8v a = *(const bf8v*)(eat + (size_t)(jt + cq) * DE + quad * 8);
        __builtin_amdgcn_s_setprio(1);
#pragma unroll
        for (int ct = 0; ct < 8; ct++) {
            bf8v b = *(const bf8v*)(WeT + (size_t)(ct * 16 + cq) * DE + quad * 8);
            f4v z; z = 0.0f;
            f4v r = __builtin_amdgcn_mfma_f32_16x16x32_bf16(a, b, z, 0, 0, 0);
            int col = ct * 16 + cq;
            float b_ = bcv[col];
#pragma unroll
            for (int i = 0; i < 4; i++)
                trw[(quad * 4 + i) * 136 + col] = f2bf(r[i] + b_);
        }
        __builtin_amdgcn_s_setprio(0);
    }
    // ---- B: prefetch all 16 src-row gathers, then gelu + segmented sums ----
    uint nwv[16];
#pragma unroll
    for (int r = 0; r < 16; r++)
        nwv[r] = *(const uint*)(slotA + (size_t)sd[w][r].x * DD + 2 * lane);
    float a0 = 0.0f, a1 = 0.0f;
    int rstart = 0;
#pragma unroll
    for (int r = 0; r < 16; r++) {
        int dcur = sd[w][r].y;
        uint em = *(const uint*)(trw + r * 136 + 2 * lane);
        uint nw = nwv[r];
        a0 += gelu_t(bf2f((ushort)(em & 0xffffu)) + bf2f((ushort)(nw & 0xffffu)));
        a1 += gelu_t(bf2f((ushort)(em >> 16)) + bf2f((ushort)(nw >> 16)));
        bool flush = (r == 15) || (sd[w][r + 1].y != dcur);
        if (flush) {
            float* p = aggf + (size_t)dcur * DD + 2 * lane;
            if (rstart > 0 && r < 15) {
                float2 st; st.x = a0; st.y = a1;
                *(float2*)p = st;                  // sole writer: plain store
            } else {
                atomicAdd(p, a0);
                atomicAdd(p + 1, a1);
            }
            a0 = 0.0f; a1 = 0.0f; rstart = r + 1;
        }
    }
}

// ---------------- mega node MLP: round-6 configuration (16 rows/wave, 3 blk/CU) ----
// Measured optimum of this structure: r6=89us vs r7 (32row,2blk)=110 vs r8
// (32row+reg-fragments, spills)=277. Do not raise rows/wave or LDS.
template<int FUSE>
__global__ __launch_bounds__(256, 3) void k_mlp(
    float* __restrict__ aggf, const float* __restrict__ invdeg,
    const ushort* __restrict__ w2T, const float* __restrict__ b2,
    const float* __restrict__ flag,
    const ushort* __restrict__ u1T, const float* __restrict__ bu1,
    const ushort* __restrict__ u2T, const float* __restrict__ bu2,
    float* __restrict__ node,
    const float* __restrict__ lg, const float* __restrict__ lb,
    const ushort* __restrict__ w1nT, ushort* __restrict__ slotA, int M)
{
    __shared__ __align__(16) ushort lwgt[16384];   // 32KB staged weight tile
    __shared__ ushort tr[4][16 * 136];
    int tid = threadIdx.x, lane = tid & 63, w = tid >> 6;
    int base = (blockIdx.x * 4 + w) * 16;
    bool act = base < M;
    int cq = lane & 15, quad = lane >> 4;
    ushort* trw = tr[w];
    f4v acc[8];
    bf8v a[4], a2[4];

    // ---- phase 0: B1 = (aggf*invdeg) @ msg_w2 ----
    stage_w<4>(lwgt, w2T, DD, w, lane);
    if (act) {
        float iv = invdeg[base + cq];
        float* Af = aggf + (size_t)(base + cq) * DD;
#pragma unroll
        for (int kc = 0; kc < 4; kc++) {
            float4 v0 = *(const float4*)(Af + kc * 32 + quad * 8);
            float4 v1 = *(const float4*)(Af + kc * 32 + quad * 8 + 4);
            bf8v t;
            t[0]=(short)f2bf(v0.x*iv); t[1]=(short)f2bf(v0.y*iv);
            t[2]=(short)f2bf(v0.z*iv); t[3]=(short)f2bf(v0.w*iv);
            t[4]=(short)f2bf(v1.x*iv); t[5]=(short)f2bf(v1.y*iv);
            t[6]=(short)f2bf(v1.z*iv); t[7]=(short)f2bf(v1.w*iv);
            a[kc] = t;
        }
        if (FUSE) {
            float4 z4; z4.x = 0.0f; z4.y = 0.0f; z4.z = 0.0f; z4.w = 0.0f;
#pragma unroll
            for (int kc = 0; kc < 4; kc++) {
                *(float4*)(Af + kc * 32 + quad * 8) = z4;
                *(float4*)(Af + kc * 32 + quad * 8 + 4) = z4;
            }
        }
    }
    __syncthreads();
    if (act) {
#pragma unroll
        for (int ct = 0; ct < 8; ct++) acc[ct] = 0.0f;
        gemm_l(a, lwgt, cq, quad, acc);
        float fl[4];
#pragma unroll
        for (int i = 0; i < 4; i++) fl[i] = flag[base + quad * 4 + i];
#pragma unroll
        for (int ct = 0; ct < 8; ct++) {
            int col = ct * 16 + cq;
            float b_ = b2[col];
#pragma unroll
            for (int i = 0; i < 4; i++)
                trw[(quad * 4 + i) * 136 + col] = f2bf(acc[ct][i] + fl[i] * b_);
        }
#pragma unroll
        for (int kc = 0; kc < 4; kc++)
            a2[kc] = *(const bf8v*)(trw + cq * 136 + kc * 32 + quad * 8);
    }

    // ---- u = gelu(a2@u1 + bu1) @ u2, two 128-col halves ----
    f4v accU[8];
#pragma unroll
    for (int ct = 0; ct < 8; ct++) accU[ct] = 0.0f;
#pragma unroll
    for (int h = 0; h < 2; h++) {
        __syncthreads();                            // readers done with lwgt
        stage_w<4>(lwgt, u1T + (size_t)h * 128 * DD, DD, w, lane);
        __syncthreads();                            // u1 half staged
        bf8v tf[4];
        if (act) {
#pragma unroll
            for (int ct = 0; ct < 8; ct++) acc[ct] = 0.0f;
            gemm_l(a2, lwgt, cq, quad, acc);
#pragma unroll
            for (int ct = 0; ct < 8; ct++) {
                int col = ct * 16 + cq;
                float b_ = bu1[h * 128 + col];
#pragma unroll
                for (int i = 0; i < 4; i++)
                    trw[(quad * 4 + i) * 136 + col] = f2bf(gelu_f(acc[ct][i] + b_));
            }
#pragma unroll
            for (int kc = 0; kc < 4; kc++)
                tf[kc] = *(const bf8v*)(trw + cq * 136 + kc * 32 + quad * 8);
        }
        __syncthreads();
        stage_w<4>(lwgt, u2T + (size_t)h * 128, 256, w, lane);   // u2 half, stride 256
        __syncthreads();
        if (act) gemm_l(tf, lwgt, cq, quad, accU);
    }

    // ---- resid + LN ----
    int r0 = base + quad * 4;
    if (act) {
        float xv[8][4], lgc[8], lbc[8];
#pragma unroll
        for (int ct = 0; ct < 8; ct++) {
            int col = ct * 16 + cq;
            float b_ = bu2[col];
            lgc[ct] = lg[col]; lbc[ct] = lb[col];
#pragma unroll
            for (int i = 0; i < 4; i++)
                xv[ct][i] = accU[ct][i] + b_ + node[(size_t)(r0 + i) * DD + col];
        }
#pragma unroll
        for (int i = 0; i < 4; i++) {
            float s = 0.0f;
#pragma unroll
            for (int ct = 0; ct < 8; ct++) s += xv[ct][i];
            s += __shfl_xor(s, 1); s += __shfl_xor(s, 2);
            s += __shfl_xor(s, 4); s += __shfl_xor(s, 8);
            float m = s * (1.0f / 128.0f);
            float vv = 0.0f;
#pragma unroll
            for (int ct = 0; ct < 8; ct++) { float d = xv[ct][i] - m; vv += d * d; }
            vv += __shfl_xor(vv, 1); vv += __shfl_xor(vv, 2);
            vv += __shfl_xor(vv, 4); vv += __shfl_xor(vv, 8);
            float inv = rsqrtf(vv * (1.0f / 128.0f) + 1e-5f);
#pragma unroll
            for (int ct = 0; ct < 8; ct++) {
                int col = ct * 16 + cq;
                float y = (xv[ct][i] - m) * inv * lgc[ct] + lbc[ct];
                node[(size_t)(r0 + i) * DD + col] = y;
                if (FUSE) trw[(quad * 4 + i) * 136 + col] = f2bf(y);
            }
        }
    }

    // ---- fused next-layer nodeW1 ----
    if (FUSE) {
        __syncthreads();
        stage_w<4>(lwgt, w1nT, DD, w, lane);
        __syncthreads();
        if (act) {
            bf8v nf[4];
#pragma unroll
            for (int kc = 0; kc < 4; kc++)
                nf[kc] = *(const bf8v*)(trw + cq * 136 + kc * 32 + quad * 8);
#pragma unroll
            for (int ct = 0; ct < 8; ct++) acc[ct] = 0.0f;
            gemm_l(nf, lwgt, cq, quad, acc);
#pragma unroll
            for (int ct = 0; ct < 8; ct++) {
                int col = ct * 16 + cq;
#pragma unroll
                for (int i = 0; i < 4; i++)
                    slotA[(size_t)(r0 + i) * DD + col] = f2bf(acc[ct][i]);
            }
        }
    }
}

// ---------------- pooling: 128 chunks/segment for latency hiding ----------------
__global__ void k_pool_partial(const float* __restrict__ node, float* __restrict__ partial) {
    int seg = blockIdx.x, chunk = blockIdx.y, j = threadIdx.x;
    int segbase = seg * 14286;
    int segcnt = (seg == 6) ? 14284 : 14286;
    const int per = 112;                       // ceil(14286/128)
    int lo = chunk * per, hi = min(lo + per, segcnt);
    float s = 0.0f;
    for (int r = lo; r < hi; r++) s += node[(size_t)(segbase + r) * DD + j];
    partial[(size_t)(seg * 128 + chunk) * DD + j] = s;
}

__global__ void k_pool_final(const float* __restrict__ partial, const float* __restrict__ g,
                             const float* __restrict__ b, float* __restrict__ out) {
    __shared__ float red[128];
    int j = threadIdx.x;
    float tok[8];
    float tot = 0.0f;
#pragma unroll
    for (int s = 0; s < 7; s++) {
        float v = 0.0f;
        for (int c = 0; c < 128; c++) v += partial[(size_t)(s * 128 + c) * DD + j];
        tok[1 + s] = v / ((s == 6) ? 14284.0f : 14286.0f);
        tot += v;
    }
    tok[0] = tot / 100000.0f;
    for (int t = 0; t < 8; t++) {
        float x = tok[t];
        red[j] = x; __syncthreads();
        for (int off = 64; off > 0; off >>= 1) {
            if (j < off) red[j] += red[j + off];
            __syncthreads();
        }
        float m = red[0] / 128.0f;
        __syncthreads();
        float d = x - m;
        red[j] = d * d; __syncthreads();
        for (int off = 64; off > 0; off >>= 1) {
            if (j < off) red[j] += red[j + off];
            __syncthreads();
        }
        float var = red[0] / 128.0f;
        __syncthreads();
        out[t * DD + j] = d * rsqrtf(var + 1e-5f) * g[j] + b[j];
    }
}

extern "C" void kernel_launch(void* const* d_in, const int* in_sizes, int n_in,
                              void* d_out, int out_size, void* d_ws, size_t ws_size,
                              hipStream_t stream) {
    const float* x         = (const float*)d_in[0];
    const int*   ei        = (const int*)d_in[1];
    const float* edge_attr = (const float*)d_in[2];
    const float* node_w    = (const float*)d_in[3];
    const float* node_b    = (const float*)d_in[4];
    const float* edge_w    = (const float*)d_in[5];
    const float* edge_b    = (const float*)d_in[6];
    const float* msg_w1    = (const float*)d_in[7];
    const float* msg_b1    = (const float*)d_in[8];
    const float* msg_w2    = (const float*)d_in[9];
    const float* msg_b2    = (const float*)d_in[10];
    const float* upd_w1    = (const float*)d_in[11];
    const float* upd_b1    = (const float*)d_in[12];
    const float* upd_w2    = (const float*)d_in[13];
    const float* upd_b2    = (const float*)d_in[14];
    const float* ln_g      = (const float*)d_in[15];
    const float* ln_b      = (const float*)d_in[16];
    const float* out_g     = (const float*)d_in[17];
    const float* out_b     = (const float*)d_in[18];
    float* out = (float*)d_out;

    // ---- workspace layout ----
    char* pw = (char*)d_ws;
    auto alloc = [&](size_t bytes) -> void* {
        void* r = (void*)pw;
        pw += (bytes + 255) & ~(size_t)255;
        return r;
    };
    float*  node_f  = (float*) alloc((size_t)N_NODES * DD * 4);
    ushort* slotA   = (ushort*)alloc((size_t)N_NODES * DD * 2);
    float*  aggf    = (float*) alloc((size_t)N_NODES * DD * 4);
    ushort* eat     = (ushort*)alloc((size_t)N_EDGES * DE * 2);
    float*  bc      = (float*) alloc((size_t)3 * DD * 4);
    ushort* WeT     = (ushort*)alloc((size_t)3 * DD * DE * 2);
    float*  partial = (float*) alloc((size_t)7 * 128 * DD * 4);
    float*  degflag = (float*) alloc((size_t)N_NODES * 4);
    float*  invdeg  = (float*) alloc((size_t)N_NODES * 4);
    ushort* node_wT = (ushort*)alloc((size_t)DD * DD * 2);
    ushort* msg_w1T = (ushort*)alloc((size_t)3 * DD * DD * 2);
    ushort* msg_w2T = (ushort*)alloc((size_t)3 * DD * DD * 2);
    ushort* upd_w1T = (ushort*)alloc((size_t)3 * 256 * DD * 2);
    ushort* upd_w2T = (ushort*)alloc((size_t)3 * DD * 256 * 2);
    int* cnt        = (int*)   alloc((size_t)N_NODES * 4);
    int* cursor     = (int*)   alloc((size_t)N_NODES * 4);
    int* bsum       = (int*)   alloc((size_t)512 * 4);
    int* esrc       = (int*)   alloc((size_t)N_EDGES * 4);
    int* edst       = (int*)   alloc((size_t)N_EDGES * 4);

    hipMemsetAsync(cnt, 0, N_NODES * sizeof(int), stream);
    hipMemsetAsync(aggf, 0, (size_t)N_NODES * DD * 4, stream);   // layer-0 agg init
    k_count  <<<(N_EDGES + 255) / 256, 256, 0, stream>>>(ei, cnt);
    k_scan1  <<<SCAN_NB, SCAN_B, 0, stream>>>(cnt, bsum);
    k_scan2  <<<1, 512, 0, stream>>>(bsum);
    k_scan3  <<<SCAN_NB, SCAN_B, 0, stream>>>(cnt, bsum, cursor, degflag, invdeg);
    k_scatter<<<(N_EDGES + 255) / 256, 256, 0, stream>>>(ei, edge_attr, cursor, esrc, edst, eat);
    k_prep   <<<dim3(DE + 1, 3), DD, 0, stream>>>(edge_w, edge_b, msg_w1, msg_b1, WeT, bc);

    // batched weight transposes -> bf16 [out][in]
    TPack tp;
    tp.d[0] = { node_w, node_wT, DD, DD };
    for (int l = 0; l < 3; l++) {
        tp.d[1 + l*4 + 0] = { msg_w1 + (size_t)l*DD*DD,  msg_w1T + (size_t)l*DD*DD,  DD, DD };
        tp.d[1 + l*4 + 1] = { msg_w2 + (size_t)l*DD*DD,  msg_w2T + (size_t)l*DD*DD,  DD, DD };
        tp.d[1 + l*4 + 2] = { upd_w1 + (size_t)l*DD*256, upd_w1T + (size_t)l*256*DD, DD, 256 };
        tp.d[1 + l*4 + 3] = { upd_w2 + (size_t)l*256*DD, upd_w2T + (size_t)l*DD*256, 256, DD };
    }
    k_tball<<<dim3(128, 13), 256, 0, stream>>>(tp);

    const int GB = (N_NODES / 16 + 3) / 4;     // 1563 (16 rows/wave)
    const int MSG_GB = N_EDGES / 64;           // 10000
    k_embed<<<GB, 256, 0, stream>>>(x, node_wT, node_b, msg_w1T, node_f, slotA, N_NODES);

    for (int l = 0; l < 3; l++) {
        k_msg<<<MSG_GB, 256, 0, stream>>>(eat, WeT + (size_t)l*DD*DE,
            bc + (size_t)l*DD, esrc, edst, slotA, aggf);
        if (l < 2) {
            k_mlp<1><<<GB, 256, 0, stream>>>(aggf, invdeg,
                msg_w2T + (size_t)l*DD*DD, msg_b2 + (size_t)l*DD, degflag,
                upd_w1T + (size_t)l*256*DD, upd_b1 + (size_t)l*256,
                upd_w2T + (size_t)l*DD*256, upd_b2 + (size_t)l*DD,
                node_f, ln_g + (size_t)l*DD, ln_b + (size_t)l*DD,
                msg_w1T + (size_t)(l+1)*DD*DD, slotA, N_NODES);
        } else {
            k_mlp<0><<<GB, 256, 0, stream>>>(aggf, invdeg,
                msg_w2T + (size_t)l*DD*DD, msg_b2 + (size_t)l*DD, degflag,
                upd_w1T + (size_t)l*256*DD, upd_b1 + (size_t)l*256,
                upd_w2T + (size_t)l*DD*256, upd_b2 + (size_t)l*DD,
                node_f, ln_g + (size_t)l*DD, ln_b + (size_t)l*DD,
                msg_w1T, slotA, N_NODES);
        }
    }

    k_pool_partial<<<dim3(7, 128), DD, 0, stream>>>(node_f, partial);
    k_pool_final  <<<1, DD, 0, stream>>>(partial, out_g, out_b, out);
}

// Round 10
// 772.051 us; speedup vs baseline: 1.7040x; 1.0601x over previous
//
#include <hip/hip_runtime.h>
#include <hip/hip_bf16.h>

#define N_NODES 100000
#define N_EDGES 640000
#define DD 128
#define DE 32
#define SCAN_B 256
#define SCAN_NB ((N_NODES + SCAN_B - 1) / SCAN_B)   // 391

typedef __attribute__((ext_vector_type(8))) short bf8v;
typedef __attribute__((ext_vector_type(4))) float f4v;

__device__ __forceinline__ float gelu_f(float x) {
    return 0.5f * x * (1.0f + erff(x * 0.70710678118654752f));
}
// gelu(x) = x * sigmoid(2y): z = x*(c1 + c2*x^2) in log2 domain, 8 VALU ops.
__device__ __forceinline__ float gelu_t(float x) {
    float x2 = x * x;
    float z = x * fmaf(0.1029437f, x2, 2.3022082f);
    float e = __builtin_amdgcn_exp2f(z);
    float r = __builtin_amdgcn_rcpf(e + 1.0f);
    return fmaf(-x, r, x);
}
__device__ __forceinline__ float bf2f(ushort u) {
    union { uint u; float f; } t; t.u = ((uint)u) << 16; return t.f;
}
__device__ __forceinline__ ushort f2bf(float f) {
    union { float f; uint u; } t; t.f = f;
    uint r = (t.u + 0x7fffu + ((t.u >> 16) & 1u)) >> 16;
    return (ushort)r;
}

// ---- cooperative weight staging: 128x128 bf16 tile -> 32KB LDS, XOR-swizzled ----
// LDS dest linear (wave-uniform base + lane*16); swizzle applied to GLOBAL source.
template<int NW>
__device__ __forceinline__ void stage_w(ushort* lwgt, const ushort* __restrict__ src,
                                        int stride, int w, int lane) {
    constexpr int SEG = 32768 / NW;        // bytes per wave
#pragma unroll
    for (int k = 0; k < SEG / 1024; k++) {
        int o = w * SEG + k * 1024 + lane * 16;      // linear LDS byte offset
        int row = o >> 8;                            // 0..127
        int swz = o ^ ((row & 7) << 4);              // involution
        const ushort* g = src + (size_t)row * stride + ((swz & 255) >> 1);
        __builtin_amdgcn_global_load_lds(
            (const __attribute__((address_space(1))) void*)g,
            (__attribute__((address_space(3))) void*)(lwgt + (w * SEG + k * 1024) / 2),
            16, 0, 0);
    }
}

// ---- 16-row x 128-col GEMM from staged LDS weights ----
__device__ __forceinline__ void gemm_l(const bf8v* a, const ushort* lwgt,
                                       int cq, int quad, f4v* acc) {
    const char* lb = (const char*)lwgt;
    int sw = (cq & 7) << 4;
    __builtin_amdgcn_s_setprio(1);
#pragma unroll
    for (int ct = 0; ct < 8; ct++) {
#pragma unroll
        for (int kc = 0; kc < 4; kc++) {
            int addr = (((ct * 16 + cq) << 8) + (kc << 6) + (quad << 4)) ^ sw;
            acc[ct] = __builtin_amdgcn_mfma_f32_16x16x32_bf16(a[kc],
                *(const bf8v*)(lb + addr), acc[ct], 0, 0, 0);
        }
    }
    __builtin_amdgcn_s_setprio(0);
}

// ---------------- CSR build ----------------
__global__ void k_count(const int* __restrict__ ei, int* __restrict__ cnt) {
    int e = blockIdx.x * blockDim.x + threadIdx.x;
    if (e < N_EDGES) atomicAdd(&cnt[ei[N_EDGES + e]], 1);
}

__global__ void k_scan1(const int* __restrict__ cnt, int* __restrict__ bsum) {
    __shared__ int s[SCAN_B];
    int i = blockIdx.x * SCAN_B + threadIdx.x;
    int v = (i < N_NODES) ? cnt[i] : 0;
    s[threadIdx.x] = v;
    __syncthreads();
    for (int off = SCAN_B / 2; off > 0; off >>= 1) {
        if (threadIdx.x < off) s[threadIdx.x] += s[threadIdx.x + off];
        __syncthreads();
    }
    if (threadIdx.x == 0) bsum[blockIdx.x] = s[0];
}

__global__ void k_scan2(int* __restrict__ bsum) {
    __shared__ int s[512];
    int t = threadIdx.x;
    int v = (t < SCAN_NB) ? bsum[t] : 0;
    s[t] = v;
    __syncthreads();
    for (int off = 1; off < 512; off <<= 1) {
        int u = (t >= off) ? s[t - off] : 0;
        __syncthreads();
        s[t] += u;
        __syncthreads();
    }
    if (t < SCAN_NB) bsum[t] = s[t] - v;   // exclusive
}

__global__ void k_scan3(const int* __restrict__ cnt, const int* __restrict__ bsum,
                        int* __restrict__ cursor, float* __restrict__ flag,
                        float* __restrict__ invdeg) {
    __shared__ int s[SCAN_B];
    int i = blockIdx.x * SCAN_B + threadIdx.x;
    int v = (i < N_NODES) ? cnt[i] : 0;
    s[threadIdx.x] = v;
    __syncthreads();
    for (int off = 1; off < SCAN_B; off <<= 1) {
        int u = (threadIdx.x >= off) ? s[threadIdx.x - off] : 0;
        __syncthreads();
        s[threadIdx.x] += u;
        __syncthreads();
    }
    if (i < N_NODES) {
        int excl = s[threadIdx.x] - v + bsum[blockIdx.x];
        cursor[i] = excl;
        flag[i] = (v > 0) ? 1.0f : 0.0f;
        invdeg[i] = (v > 0) ? 1.0f / (float)v : 0.0f;
    }
}

// scatter + inline edge_attr permute (fp32 -> bf16, CSR slot order)
__global__ void k_scatter(const int* __restrict__ ei, const float* __restrict__ ea,
                          int* __restrict__ cursor, int* __restrict__ esrc,
                          int* __restrict__ edst, ushort* __restrict__ eat) {
    int e = blockIdx.x * blockDim.x + threadIdx.x;
    if (e < N_EDGES) {
        int d = ei[N_EDGES + e];
        int pos = atomicAdd(&cursor[d], 1);
        esrc[pos] = ei[e];
        edst[pos] = d;
        const float* s = ea + (size_t)e * DE;
        ushort* o = eat + (size_t)pos * DE;
#pragma unroll
        for (int k = 0; k < 8; k++) {
            float4 v = *(const float4*)(s + k * 4);
            ushort4 u;
            u.x = f2bf(v.x); u.y = f2bf(v.y); u.z = f2bf(v.z); u.w = f2bf(v.w);
            *(ushort4*)(o + k * 4) = u;
        }
    }
}

// ---------------- composite edge weights: writes bf16-transposed WeT + fp32 bc ----------------
__global__ void k_prep(const float* __restrict__ edge_w, const float* __restrict__ edge_b,
                       const float* __restrict__ msg_w1, const float* __restrict__ msg_b1,
                       ushort* __restrict__ WeT, float* __restrict__ bc) {
    int j = threadIdx.x;
    int c = blockIdx.x;
    int l = blockIdx.y;
    const float* w1 = msg_w1 + (size_t)l * DD * DD;
    if (c < DE) {
        float s = 0.0f;
        for (int k = 0; k < DD; k++) s += edge_w[c*DD + k] * w1[k*DD + j];
        WeT[((size_t)l*DD + j)*DE + c] = f2bf(s);     // [l][j(out)][c(k)]
    } else {
        float s = msg_b1[l*DD + j];
        for (int k = 0; k < DD; k++) s += edge_b[k] * w1[k*DD + j];
        bc[l*DD + j] = s;
    }
}

// ---------------- batched transpose fp32 [R][C] -> bf16 [C][R] ----------------
struct TDesc { const float* src; ushort* dst; int R; int C; };
struct TPack { TDesc d[13]; };

__global__ void k_tball(TPack p) {
    TDesc t = p.d[blockIdx.y];
    int idx = blockIdx.x * 256 + threadIdx.x;
    if (idx < t.R * t.C) {
        int r = idx / t.C, c = idx % t.C;
        t.dst[(size_t)c * t.R + r] = f2bf(t.src[idx]);
    }
}

// ---------------- embed + fused nodeW1(l=0), LDS-staged weights (4-wave) ----------------
__global__ __launch_bounds__(256, 3) void k_embed(
    const float* __restrict__ x, const ushort* __restrict__ WT,
    const float* __restrict__ bias, const ushort* __restrict__ W1T,
    float* __restrict__ node, ushort* __restrict__ slotA, int M)
{
    __shared__ __align__(16) ushort lwgt[16384];   // 32KB staged weight tile
    __shared__ ushort tr[4][16 * 136];
    int tid = threadIdx.x, lane = tid & 63, w = tid >> 6;
    int base = (blockIdx.x * 4 + w) * 16;
    bool act = base < M;
    int cq = lane & 15, quad = lane >> 4;
    ushort* trw = tr[w];
    f4v acc[8];
    bf8v a[4];

    stage_w<4>(lwgt, WT, DD, w, lane);              // phase 0 weights in flight
    if (act) {
        const float* Af = x + (size_t)(base + cq) * DD;
#pragma unroll
        for (int kc = 0; kc < 4; kc++) {
            float4 v0 = *(const float4*)(Af + kc * 32 + quad * 8);
            float4 v1 = *(const float4*)(Af + kc * 32 + quad * 8 + 4);
            bf8v t;
            t[0]=(short)f2bf(v0.x); t[1]=(short)f2bf(v0.y); t[2]=(short)f2bf(v0.z); t[3]=(short)f2bf(v0.w);
            t[4]=(short)f2bf(v1.x); t[5]=(short)f2bf(v1.y); t[6]=(short)f2bf(v1.z); t[7]=(short)f2bf(v1.w);
            a[kc] = t;
        }
    }
    __syncthreads();                                // staging complete
    int r0 = base + quad * 4;
    bf8v a2[4];
    if (act) {
#pragma unroll
        for (int ct = 0; ct < 8; ct++) acc[ct] = 0.0f;
        gemm_l(a, lwgt, cq, quad, acc);
#pragma unroll
        for (int ct = 0; ct < 8; ct++) {
            int col = ct * 16 + cq;
            float b_ = bias[col];
#pragma unroll
            for (int i = 0; i < 4; i++) {
                float v = acc[ct][i] + b_;
                node[(size_t)(r0 + i) * DD + col] = v;
                trw[(quad * 4 + i) * 136 + col] = f2bf(v);
            }
        }
#pragma unroll
        for (int kc = 0; kc < 4; kc++)
            a2[kc] = *(const bf8v*)(trw + cq * 136 + kc * 32 + quad * 8);
    }
    __syncthreads();                                // all waves done reading lwgt
    stage_w<4>(lwgt, W1T, DD, w, lane);
    __syncthreads();
    if (act) {
#pragma unroll
        for (int ct = 0; ct < 8; ct++) acc[ct] = 0.0f;
        gemm_l(a2, lwgt, cq, quad, acc);
#pragma unroll
        for (int ct = 0; ct < 8; ct++) {
            int col = ct * 16 + cq;
#pragma unroll
            for (int i = 0; i < 4; i++)
                slotA[(size_t)(r0 + i) * DD + col] = f2bf(acc[ct][i]);
        }
    }
}

// ---------------- fused edge message + segmented aggregation (32 edges/wave) ----------------
// Each wave: two 16-edge MFMA batches sequentially reuse one wave-private tr
// buffer; dst-run accumulator carried across the batch boundary. Interior runs
// (within the 32-edge window) are sole-writer -> plain float2 store; boundary
// runs use atomicAdd. Halves boundary-atomic count and per-edge fixed overhead
// vs the 16-edge version.
__global__ __launch_bounds__(256) void k_msg(
    const ushort* __restrict__ eat,
    const ushort* __restrict__ WeT, const float* __restrict__ bcv,
    const int* __restrict__ esrc, const int* __restrict__ edst,
    const ushort* __restrict__ slotA, float* __restrict__ aggf)
{
    __shared__ ushort tr[4][16 * 136];
    __shared__ int2 sd[4][32];
    int tid = threadIdx.x, lane = tid & 63, w = tid >> 6;
    int jt = (blockIdx.x * 4 + w) * 32;
    int cq = lane & 15, quad = lane >> 4;
    ushort* trw = tr[w];

    if (lane < 32) {
        int2 v; v.x = esrc[jt + lane]; v.y = edst[jt + lane];
        sd[w][lane] = v;
    }
    float a0 = 0.0f, a1 = 0.0f;
    int rstart = 0;
#pragma unroll
    for (int half = 0; half < 2; half++) {
        int hb = half * 16;
        // ---- A: emb1 for edges [jt+hb, jt+hb+16) via MFMA (K=32) ----
        {
            bf8v a = *(const bf8v*)(eat + (size_t)(jt + hb + cq) * DE + quad * 8);
            __builtin_amdgcn_s_setprio(1);
#pragma unroll
            for (int ct = 0; ct < 8; ct++) {
                bf8v b = *(const bf8v*)(WeT + (size_t)(ct * 16 + cq) * DE + quad * 8);
                f4v z; z = 0.0f;
                f4v r = __builtin_amdgcn_mfma_f32_16x16x32_bf16(a, b, z, 0, 0, 0);
                int col = ct * 16 + cq;
                float b_ = bcv[col];
#pragma unroll
                for (int i = 0; i < 4; i++)
                    trw[(quad * 4 + i) * 136 + col] = f2bf(r[i] + b_);
            }
            __builtin_amdgcn_s_setprio(0);
        }
        // ---- B: prefetch 16 src-row gathers, then gelu + segmented sums ----
        uint nwv[16];
#pragma unroll
        for (int r = 0; r < 16; r++)
            nwv[r] = *(const uint*)(slotA + (size_t)sd[w][hb + r].x * DD + 2 * lane);
#pragma unroll
        for (int r = 0; r < 16; r++) {
            int g = hb + r;
            int dcur = sd[w][g].y;
            uint em = *(const uint*)(trw + r * 136 + 2 * lane);
            uint nw = nwv[r];
            union { uint u; float f; } c0, c1, c2, c3;
            c0.u = em << 16; c1.u = em & 0xffff0000u;
            c2.u = nw << 16; c3.u = nw & 0xffff0000u;
            a0 += gelu_t(c0.f + c2.f);
            a1 += gelu_t(c1.f + c3.f);
            bool flush = (g == 31) || (sd[w][g + 1].y != dcur);
            if (flush) {
                float* p = aggf + (size_t)dcur * DD + 2 * lane;
                if (rstart > 0 && g < 31) {
                    float2 st; st.x = a0; st.y = a1;
                    *(float2*)p = st;              // sole writer: plain store
                } else {
                    atomicAdd(p, a0);
                    atomicAdd(p + 1, a1);
                }
                a0 = 0.0f; a1 = 0.0f; rstart = g + 1;
            }
        }
    }
}

// ---------------- mega node MLP: round-6 configuration (16 rows/wave, 3 blk/CU) ----
// Measured optimum of this structure: r6=89us vs r7 (32row,2blk)=110 vs r8
// (32row+reg-fragments, spills)=277. Do not raise rows/wave or LDS.
template<int FUSE>
__global__ __launch_bounds__(256, 3) void k_mlp(
    float* __restrict__ aggf, const float* __restrict__ invdeg,
    const ushort* __restrict__ w2T, const float* __restrict__ b2,
    const float* __restrict__ flag,
    const ushort* __restrict__ u1T, const float* __restrict__ bu1,
    const ushort* __restrict__ u2T, const float* __restrict__ bu2,
    float* __restrict__ node,
    const float* __restrict__ lg, const float* __restrict__ lb,
    const ushort* __restrict__ w1nT, ushort* __restrict__ slotA, int M)
{
    __shared__ __align__(16) ushort lwgt[16384];   // 32KB staged weight tile
    __shared__ ushort tr[4][16 * 136];
    int tid = threadIdx.x, lane = tid & 63, w = tid >> 6;
    int base = (blockIdx.x * 4 + w) * 16;
    bool act = base < M;
    int cq = lane & 15, quad = lane >> 4;
    ushort* trw = tr[w];
    f4v acc[8];
    bf8v a[4], a2[4];

    // ---- phase 0: B1 = (aggf*invdeg) @ msg_w2 ----
    stage_w<4>(lwgt, w2T, DD, w, lane);
    if (act) {
        float iv = invdeg[base + cq];
        float* Af = aggf + (size_t)(base + cq) * DD;
#pragma unroll
        for (int kc = 0; kc < 4; kc++) {
            float4 v0 = *(const float4*)(Af + kc * 32 + quad * 8);
            float4 v1 = *(const float4*)(Af + kc * 32 + quad * 8 + 4);
            bf8v t;
            t[0]=(short)f2bf(v0.x*iv); t[1]=(short)f2bf(v0.y*iv);
            t[2]=(short)f2bf(v0.z*iv); t[3]=(short)f2bf(v0.w*iv);
            t[4]=(short)f2bf(v1.x*iv); t[5]=(short)f2bf(v1.y*iv);
            t[6]=(short)f2bf(v1.z*iv); t[7]=(short)f2bf(v1.w*iv);
            a[kc] = t;
        }
        if (FUSE) {
            float4 z4; z4.x = 0.0f; z4.y = 0.0f; z4.z = 0.0f; z4.w = 0.0f;
#pragma unroll
            for (int kc = 0; kc < 4; kc++) {
                *(float4*)(Af + kc * 32 + quad * 8) = z4;
                *(float4*)(Af + kc * 32 + quad * 8 + 4) = z4;
            }
        }
    }
    __syncthreads();
    if (act) {
#pragma unroll
        for (int ct = 0; ct < 8; ct++) acc[ct] = 0.0f;
        gemm_l(a, lwgt, cq, quad, acc);
        float fl[4];
#pragma unroll
        for (int i = 0; i < 4; i++) fl[i] = flag[base + quad * 4 + i];
#pragma unroll
        for (int ct = 0; ct < 8; ct++) {
            int col = ct * 16 + cq;
            float b_ = b2[col];
#pragma unroll
            for (int i = 0; i < 4; i++)
                trw[(quad * 4 + i) * 136 + col] = f2bf(acc[ct][i] + fl[i] * b_);
        }
#pragma unroll
        for (int kc = 0; kc < 4; kc++)
            a2[kc] = *(const bf8v*)(trw + cq * 136 + kc * 32 + quad * 8);
    }

    // ---- u = gelu(a2@u1 + bu1) @ u2, two 128-col halves ----
    f4v accU[8];
#pragma unroll
    for (int ct = 0; ct < 8; ct++) accU[ct] = 0.0f;
#pragma unroll
    for (int h = 0; h < 2; h++) {
        __syncthreads();                            // readers done with lwgt
        stage_w<4>(lwgt, u1T + (size_t)h * 128 * DD, DD, w, lane);
        __syncthreads();                            // u1 half staged
        bf8v tf[4];
        if (act) {
#pragma unroll
            for (int ct = 0; ct < 8; ct++) acc[ct] = 0.0f;
            gemm_l(a2, lwgt, cq, quad, acc);
#pragma unroll
            for (int ct = 0; ct < 8; ct++) {
                int col = ct * 16 + cq;
                float b_ = bu1[h * 128 + col];
#pragma unroll
                for (int i = 0; i < 4; i++)
                    trw[(quad * 4 + i) * 136 + col] = f2bf(gelu_f(acc[ct][i] + b_));
            }
#pragma unroll
            for (int kc = 0; kc < 4; kc++)
                tf[kc] = *(const bf8v*)(trw + cq * 136 + kc * 32 + quad * 8);
        }
        __syncthreads();
        stage_w<4>(lwgt, u2T + (size_t)h * 128, 256, w, lane);   // u2 half, stride 256
        __syncthreads();
        if (act) gemm_l(tf, lwgt, cq, quad, accU);
    }

    // ---- resid + LN ----
    int r0 = base + quad * 4;
    if (act) {
        float xv[8][4], lgc[8], lbc[8];
#pragma unroll
        for (int ct = 0; ct < 8; ct++) {
            int col = ct * 16 + cq;
            float b_ = bu2[col];
            lgc[ct] = lg[col]; lbc[ct] = lb[col];
#pragma unroll
            for (int i = 0; i < 4; i++)
                xv[ct][i] = accU[ct][i] + b_ + node[(size_t)(r0 + i) * DD + col];
        }
#pragma unroll
        for (int i = 0; i < 4; i++) {
            float s = 0.0f;
#pragma unroll
            for (int ct = 0; ct < 8; ct++) s += xv[ct][i];
            s += __shfl_xor(s, 1); s += __shfl_xor(s, 2);
            s += __shfl_xor(s, 4); s += __shfl_xor(s, 8);
            float m = s * (1.0f / 128.0f);
            float vv = 0.0f;
#pragma unroll
            for (int ct = 0; ct < 8; ct++) { float d = xv[ct][i] - m; vv += d * d; }
            vv += __shfl_xor(vv, 1); vv += __shfl_xor(vv, 2);
            vv += __shfl_xor(vv, 4); vv += __shfl_xor(vv, 8);
            float inv = rsqrtf(vv * (1.0f / 128.0f) + 1e-5f);
#pragma unroll
            for (int ct = 0; ct < 8; ct++) {
                int col = ct * 16 + cq;
                float y = (xv[ct][i] - m) * inv * lgc[ct] + lbc[ct];
                node[(size_t)(r0 + i) * DD + col] = y;
                if (FUSE) trw[(quad * 4 + i) * 136 + col] = f2bf(y);
            }
        }
    }

    // ---- fused next-layer nodeW1 ----
    if (FUSE) {
        __syncthreads();
        stage_w<4>(lwgt, w1nT, DD, w, lane);
        __syncthreads();
        if (act) {
            bf8v nf[4];
#pragma unroll
            for (int kc = 0; kc < 4; kc++)
                nf[kc] = *(const bf8v*)(trw + cq * 136 + kc * 32 + quad * 8);
#pragma unroll
            for (int ct = 0; ct < 8; ct++) acc[ct] = 0.0f;
            gemm_l(nf, lwgt, cq, quad, acc);
#pragma unroll
            for (int ct = 0; ct < 8; ct++) {
                int col = ct * 16 + cq;
#pragma unroll
                for (int i = 0; i < 4; i++)
                    slotA[(size_t)(r0 + i) * DD + col] = f2bf(acc[ct][i]);
            }
        }
    }
}

// ---------------- pooling: 128 chunks/segment for latency hiding ----------------
__global__ void k_pool_partial(const float* __restrict__ node, float* __restrict__ partial) {
    int seg = blockIdx.x, chunk = blockIdx.y, j = threadIdx.x;
    int segbase = seg * 14286;
    int segcnt = (seg == 6) ? 14284 : 14286;
    const int per = 112;                       // ceil(14286/128)
    int lo = chunk * per, hi = min(lo + per, segcnt);
    float s = 0.0f;
    for (int r = lo; r < hi; r++) s += node[(size_t)(segbase + r) * DD + j];
    partial[(size_t)(seg * 128 + chunk) * DD + j] = s;
}

__global__ void k_pool_final(const float* __restrict__ partial, const float* __restrict__ g,
                             const float* __restrict__ b, float* __restrict__ out) {
    __shared__ float red[128];
    int j = threadIdx.x;
    float tok[8];
    float tot = 0.0f;
#pragma unroll
    for (int s = 0; s < 7; s++) {
        float v = 0.0f;
        for (int c = 0; c < 128; c++) v += partial[(size_t)(s * 128 + c) * DD + j];
        tok[1 + s] = v / ((s == 6) ? 14284.0f : 14286.0f);
        tot += v;
    }
    tok[0] = tot / 100000.0f;
    for (int t = 0; t < 8; t++) {
        float x = tok[t];
        red[j] = x; __syncthreads();
        for (int off = 64; off > 0; off >>= 1) {
            if (j < off) red[j] += red[j + off];
            __syncthreads();
        }
        float m = red[0] / 128.0f;
        __syncthreads();
        float d = x - m;
        red[j] = d * d; __syncthreads();
        for (int off = 64; off > 0; off >>= 1) {
            if (j < off) red[j] += red[j + off];
            __syncthreads();
        }
        float var = red[0] / 128.0f;
        __syncthreads();
        out[t * DD + j] = d * rsqrtf(var + 1e-5f) * g[j] + b[j];
    }
}

extern "C" void kernel_launch(void* const* d_in, const int* in_sizes, int n_in,
                              void* d_out, int out_size, void* d_ws, size_t ws_size,
                              hipStream_t stream) {
    const float* x         = (const float*)d_in[0];
    const int*   ei        = (const int*)d_in[1];
    const float* edge_attr = (const float*)d_in[2];
    const float* node_w    = (const float*)d_in[3];
    const float* node_b    = (const float*)d_in[4];
    const float* edge_w    = (const float*)d_in[5];
    const float* edge_b    = (const float*)d_in[6];
    const float* msg_w1    = (const float*)d_in[7];
    const float* msg_b1    = (const float*)d_in[8];
    const float* msg_w2    = (const float*)d_in[9];
    const float* msg_b2    = (const float*)d_in[10];
    const float* upd_w1    = (const float*)d_in[11];
    const float* upd_b1    = (const float*)d_in[12];
    const float* upd_w2    = (const float*)d_in[13];
    const float* upd_b2    = (const float*)d_in[14];
    const float* ln_g      = (const float*)d_in[15];
    const float* ln_b      = (const float*)d_in[16];
    const float* out_g     = (const float*)d_in[17];
    const float* out_b     = (const float*)d_in[18];
    float* out = (float*)d_out;

    // ---- workspace layout ----
    char* pw = (char*)d_ws;
    auto alloc = [&](size_t bytes) -> void* {
        void* r = (void*)pw;
        pw += (bytes + 255) & ~(size_t)255;
        return r;
    };
    float*  node_f  = (float*) alloc((size_t)N_NODES * DD * 4);
    ushort* slotA   = (ushort*)alloc((size_t)N_NODES * DD * 2);
    float*  aggf    = (float*) alloc((size_t)N_NODES * DD * 4);
    ushort* eat     = (ushort*)alloc((size_t)N_EDGES * DE * 2);
    float*  bc      = (float*) alloc((size_t)3 * DD * 4);
    ushort* WeT     = (ushort*)alloc((size_t)3 * DD * DE * 2);
    float*  partial = (float*) alloc((size_t)7 * 128 * DD * 4);
    float*  degflag = (float*) alloc((size_t)N_NODES * 4);
    float*  invdeg  = (float*) alloc((size_t)N_NODES * 4);
    ushort* node_wT = (ushort*)alloc((size_t)DD * DD * 2);
    ushort* msg_w1T = (ushort*)alloc((size_t)3 * DD * DD * 2);
    ushort* msg_w2T = (ushort*)alloc((size_t)3 * DD * DD * 2);
    ushort* upd_w1T = (ushort*)alloc((size_t)3 * 256 * DD * 2);
    ushort* upd_w2T = (ushort*)alloc((size_t)3 * DD * 256 * 2);
    int* cnt        = (int*)   alloc((size_t)N_NODES * 4);
    int* cursor     = (int*)   alloc((size_t)N_NODES * 4);
    int* bsum       = (int*)   alloc((size_t)512 * 4);
    int* esrc       = (int*)   alloc((size_t)N_EDGES * 4);
    int* edst       = (int*)   alloc((size_t)N_EDGES * 4);

    hipMemsetAsync(cnt, 0, N_NODES * sizeof(int), stream);
    hipMemsetAsync(aggf, 0, (size_t)N_NODES * DD * 4, stream);   // layer-0 agg init
    k_count  <<<(N_EDGES + 255) / 256, 256, 0, stream>>>(ei, cnt);
    k_scan1  <<<SCAN_NB, SCAN_B, 0, stream>>>(cnt, bsum);
    k_scan2  <<<1, 512, 0, stream>>>(bsum);
    k_scan3  <<<SCAN_NB, SCAN_B, 0, stream>>>(cnt, bsum, cursor, degflag, invdeg);
    k_scatter<<<(N_EDGES + 255) / 256, 256, 0, stream>>>(ei, edge_attr, cursor, esrc, edst, eat);
    k_prep   <<<dim3(DE + 1, 3), DD, 0, stream>>>(edge_w, edge_b, msg_w1, msg_b1, WeT, bc);

    // batched weight transposes -> bf16 [out][in]
    TPack tp;
    tp.d[0] = { node_w, node_wT, DD, DD };
    for (int l = 0; l < 3; l++) {
        tp.d[1 + l*4 + 0] = { msg_w1 + (size_t)l*DD*DD,  msg_w1T + (size_t)l*DD*DD,  DD, DD };
        tp.d[1 + l*4 + 1] = { msg_w2 + (size_t)l*DD*DD,  msg_w2T + (size_t)l*DD*DD,  DD, DD };
        tp.d[1 + l*4 + 2] = { upd_w1 + (size_t)l*DD*256, upd_w1T + (size_t)l*256*DD, DD, 256 };
        tp.d[1 + l*4 + 3] = { upd_w2 + (size_t)l*256*DD, upd_w2T + (size_t)l*DD*256, 256, DD };
    }
    k_tball<<<dim3(128, 13), 256, 0, stream>>>(tp);

    const int GB = (N_NODES / 16 + 3) / 4;     // 1563 (16 rows/wave)
    const int MSG_GB = N_EDGES / 128;          // 5000 (32 edges/wave, 4 waves)
    k_embed<<<GB, 256, 0, stream>>>(x, node_wT, node_b, msg_w1T, node_f, slotA, N_NODES);

    for (int l = 0; l < 3; l++) {
        k_msg<<<MSG_GB, 256, 0, stream>>>(eat, WeT + (size_t)l*DD*DE,
            bc + (size_t)l*DD, esrc, edst, slotA, aggf);
        if (l < 2) {
            k_mlp<1><<<GB, 256, 0, stream>>>(aggf, invdeg,
                msg_w2T + (size_t)l*DD*DD, msg_b2 + (size_t)l*DD, degflag,
                upd_w1T + (size_t)l*256*DD, upd_b1 + (size_t)l*256,
                upd_w2T + (size_t)l*DD*256, upd_b2 + (size_t)l*DD,
                node_f, ln_g + (size_t)l*DD, ln_b + (size_t)l*DD,
                msg_w1T + (size_t)(l+1)*DD*DD, slotA, N_NODES);
        } else {
            k_mlp<0><<<GB, 256, 0, stream>>>(aggf, invdeg,
                msg_w2T + (size_t)l*DD*DD, msg_b2 + (size_t)l*DD, degflag,
                upd_w1T + (size_t)l*256*DD, upd_b1 + (size_t)l*256,
                upd_w2T + (size_t)l*DD*256, upd_b2 + (size_t)l*DD,
                node_f, ln_g + (size_t)l*DD, ln_b + (size_t)l*DD,
                msg_w1T, slotA, N_NODES);
        }
    }

    k_pool_partial<<<dim3(7, 128), DD, 0, stream>>>(node_f, partial);
    k_pool_final  <<<1, DD, 0, stream>>>(partial, out_g, out_b, out);
}